// Round 1
// baseline (1940.803 us; speedup 1.0000x reference)
//
#include <hip/hip_runtime.h>

#define CIN 128
#define COUT 64

// ---------------------------------------------------------------------------
// Kernel 1: h = x @ W_root + b ; m = x @ W_nbr
// 4 rows per 256-thread block; x rows staged in LDS; W streamed via L2.
// ---------------------------------------------------------------------------
__global__ void gemm_hm_kernel(const float* __restrict__ x,
                               const float* __restrict__ Wr,
                               const float* __restrict__ Wn,
                               const float* __restrict__ b,
                               float* __restrict__ h,
                               float* __restrict__ m,
                               int n_coarse) {
    __shared__ float xs[4][CIN];
    const int rowBase = blockIdx.x * 4;

    // cooperative load: 4 rows * 128 floats = 512 elements, 2 per thread
    for (int i = threadIdx.x; i < 4 * CIN; i += 256) {
        int r = i / CIN, k = i % CIN;
        int row = rowBase + r;
        xs[r][k] = (row < n_coarse) ? x[(long long)row * CIN + k] : 0.f;
    }
    __syncthreads();

    const int r = threadIdx.x >> 6;   // 0..3  (wave-uniform: one wave per row)
    const int c = threadIdx.x & 63;   // 0..63 channel
    const int row = rowBase + r;
    if (row >= n_coarse) return;

    float acc_h = b[c];
    float acc_m = 0.f;
#pragma unroll 8
    for (int k = 0; k < CIN; ++k) {
        const float xv = xs[r][k];              // same addr across wave -> broadcast
        acc_h += xv * Wr[k * COUT + c];         // coalesced, L2-resident (32 KB)
        acc_m += xv * Wn[k * COUT + c];
    }
    h[(long long)row * COUT + c] = acc_h;
    m[(long long)row * COUT + c] = acc_m;
}

// ---------------------------------------------------------------------------
// Kernel 2: edge scatter  h[dst] += m[src] * edge_attr   (one wave per edge)
// ---------------------------------------------------------------------------
__global__ void edge_scatter_kernel(const float* __restrict__ m,
                                    const int* __restrict__ src,
                                    const int* __restrict__ dst,
                                    const float* __restrict__ ea,
                                    float* __restrict__ h,
                                    int n_edges) {
    const int e = blockIdx.x * 4 + (threadIdx.x >> 6);
    const int c = threadIdx.x & 63;
    if (e >= n_edges) return;
    const int s = src[e];             // wave-uniform
    const int d = dst[e];
    const float w = ea[e];
    const float v = m[s * COUT + c] * w;   // coalesced 256B gather
    atomicAdd(&h[d * COUT + c], v);        // coalesced 4-line atomic
}

// ---------------------------------------------------------------------------
// Kernel 3: unpool scatter  y[pool_dst] += h[pool_src] * pool_edge_attr
// ---------------------------------------------------------------------------
__global__ void pool_scatter_kernel(const float* __restrict__ h,
                                    const int* __restrict__ psrc,
                                    const int* __restrict__ pdst,
                                    const float* __restrict__ pea,
                                    float* __restrict__ y,
                                    int n_pool) {
    const int e = blockIdx.x * 4 + (threadIdx.x >> 6);
    const int c = threadIdx.x & 63;
    if (e >= n_pool) return;
    const int s = psrc[e];
    const int d = pdst[e];
    const float w = pea[e];
    const float v = h[s * COUT + c] * w;
    atomicAdd(&y[d * COUT + c], v);
}

extern "C" void kernel_launch(void* const* d_in, const int* in_sizes, int n_in,
                              void* d_out, int out_size, void* d_ws, size_t ws_size,
                              hipStream_t stream) {
    const float* x      = (const float*)d_in[0];
    const float* W_root = (const float*)d_in[1];
    const float* W_nbr  = (const float*)d_in[2];
    const float* b      = (const float*)d_in[3];
    const int*   eidx   = (const int*)d_in[4];   // [2, E] flattened: row0=src, row1=dst
    const float* eattr  = (const float*)d_in[5];
    const int*   psrc   = (const int*)d_in[6];
    const int*   pdst   = (const int*)d_in[7];
    const float* pattr  = (const float*)d_in[8];

    const int n_coarse = in_sizes[0] / CIN;      // 200000
    const int n_edges  = in_sizes[4] / 2;        // 3200000
    const int n_pool   = in_sizes[6];            // 2400000

    const int* esrc = eidx;
    const int* edst = eidx + n_edges;

    float* h = (float*)d_ws;                               // [Nc, 64]
    float* m = h + (size_t)n_coarse * COUT;                // [Nc, 64]

    // zero the output (poisoned 0xAA before every timed launch)
    hipMemsetAsync(d_out, 0, (size_t)out_size * sizeof(float), stream);

    // 1) dense transforms
    {
        int grid = (n_coarse + 3) / 4;
        gemm_hm_kernel<<<grid, 256, 0, stream>>>(x, W_root, W_nbr, b, h, m, n_coarse);
    }
    // 2) edge aggregation into h
    {
        int grid = (n_edges + 3) / 4;
        edge_scatter_kernel<<<grid, 256, 0, stream>>>(m, esrc, edst, eattr, h, n_edges);
    }
    // 3) unpool into output
    {
        int grid = (n_pool + 3) / 4;
        pool_scatter_kernel<<<grid, 256, 0, stream>>>(h, psrc, pdst, pattr, (float*)d_out, n_pool);
    }
}

// Round 2
// 1257.140 us; speedup vs baseline: 1.5438x; 1.5438x over previous
//
#include <hip/hip_runtime.h>

#define CIN 128
#define COUT 64

// ---------------------------------------------------------------------------
// Kernel 1: h = x @ W_root + b ; m = x @ W_nbr
// 32 rows per 256-thread block; 8 rows per wave (amortizes W loads 8x);
// x rows staged in LDS, read back as float4 (wave-broadcast, conflict-free).
// ---------------------------------------------------------------------------
__global__ __launch_bounds__(256) void gemm_hm_kernel(
        const float* __restrict__ x,
        const float* __restrict__ Wr,
        const float* __restrict__ Wn,
        const float* __restrict__ b,
        float* __restrict__ h,
        float* __restrict__ m,
        int n_coarse) {
    __shared__ float xs[32][CIN];
    const int rowBase = blockIdx.x * 32;

    // cooperative stage: 32 rows * 128 floats = 16 KB, float4 loads
    if (rowBase + 32 <= n_coarse) {
        const float4* x4 = (const float4*)(x + (long long)rowBase * CIN);
        float4* xs4 = (float4*)&xs[0][0];
        for (int i = threadIdx.x; i < 32 * (CIN / 4); i += 256) xs4[i] = x4[i];
    } else {
        for (int i = threadIdx.x; i < 32 * CIN; i += 256) {
            int r = i / CIN, k = i % CIN;
            int row = rowBase + r;
            xs[r][k] = (row < n_coarse) ? x[(long long)row * CIN + k] : 0.f;
        }
    }
    __syncthreads();

    const int wv = threadIdx.x >> 6;   // wave id 0..3
    const int c  = threadIdx.x & 63;   // channel 0..63
    const int r0 = wv * 8;             // this wave's first row in the tile

    float ah[8], am[8];
    const float bias = b[c];
#pragma unroll
    for (int j = 0; j < 8; ++j) { ah[j] = bias; am[j] = 0.f; }

    for (int k = 0; k < CIN; k += 4) {
        const float wr0 = Wr[(k + 0) * COUT + c];
        const float wr1 = Wr[(k + 1) * COUT + c];
        const float wr2 = Wr[(k + 2) * COUT + c];
        const float wr3 = Wr[(k + 3) * COUT + c];
        const float wn0 = Wn[(k + 0) * COUT + c];
        const float wn1 = Wn[(k + 1) * COUT + c];
        const float wn2 = Wn[(k + 2) * COUT + c];
        const float wn3 = Wn[(k + 3) * COUT + c];
#pragma unroll
        for (int j = 0; j < 8; ++j) {
            const float4 xv = *(const float4*)&xs[r0 + j][k];
            ah[j] = fmaf(xv.x, wr0, ah[j]);
            ah[j] = fmaf(xv.y, wr1, ah[j]);
            ah[j] = fmaf(xv.z, wr2, ah[j]);
            ah[j] = fmaf(xv.w, wr3, ah[j]);
            am[j] = fmaf(xv.x, wn0, am[j]);
            am[j] = fmaf(xv.y, wn1, am[j]);
            am[j] = fmaf(xv.z, wn2, am[j]);
            am[j] = fmaf(xv.w, wn3, am[j]);
        }
    }

#pragma unroll
    for (int j = 0; j < 8; ++j) {
        const int row = rowBase + r0 + j;
        if (row < n_coarse) {
            h[row * COUT + c] = ah[j];
            m[row * COUT + c] = am[j];
        }
    }
}

// ---------------------------------------------------------------------------
// Linked-list build: entries[e] = {next, src, w}; head[dst] updated atomically.
// One packed 16-B store per edge.
// ---------------------------------------------------------------------------
__global__ __launch_bounds__(256) void build_lists_kernel(
        const int* __restrict__ src,
        const int* __restrict__ dst,
        const float* __restrict__ w,
        int* __restrict__ head,
        int4* __restrict__ entries,
        int n) {
    const int e = blockIdx.x * 256 + threadIdx.x;
    if (e >= n) return;
    const int d = dst[e];
    const int prev = atomicExch(&head[d], e);
    entries[e] = make_int4(prev, src[e], __float_as_int(w[e]), 0);
}

// ---------------------------------------------------------------------------
// Gather: one wave per destination row, lane = channel. Walk the chain,
// accumulate in registers, single coalesced row write. No atomics.
// ---------------------------------------------------------------------------
__global__ __launch_bounds__(256) void edge_gather_kernel(
        const float* __restrict__ m,
        const int* __restrict__ head,
        const int4* __restrict__ entries,
        float* __restrict__ h,
        int n_rows) {
    const int row = blockIdx.x * 4 + (threadIdx.x >> 6);
    const int c = threadIdx.x & 63;
    if (row >= n_rows) return;
    float acc = 0.f;
    int e = head[row];
    while (e >= 0) {
        const int4 en = entries[e];             // one 16-B lane-uniform load
        acc += m[en.y * COUT + c] * __int_as_float(en.z);  // coalesced 256-B gather
        e = en.x;
    }
    h[row * COUT + c] += acc;
}

__global__ __launch_bounds__(256) void pool_gather_kernel(
        const float* __restrict__ h,
        const int* __restrict__ head,
        const int4* __restrict__ entries,
        float* __restrict__ y,
        int n_rows) {
    const int row = blockIdx.x * 4 + (threadIdx.x >> 6);
    const int c = threadIdx.x & 63;
    if (row >= n_rows) return;
    float acc = 0.f;
    int e = head[row];
    while (e >= 0) {
        const int4 en = entries[e];
        acc += h[en.y * COUT + c] * __int_as_float(en.z);
        e = en.x;
    }
    y[row * COUT + c] = acc;   // full coverage -> no memset needed
}

extern "C" void kernel_launch(void* const* d_in, const int* in_sizes, int n_in,
                              void* d_out, int out_size, void* d_ws, size_t ws_size,
                              hipStream_t stream) {
    const float* x      = (const float*)d_in[0];
    const float* W_root = (const float*)d_in[1];
    const float* W_nbr  = (const float*)d_in[2];
    const float* b      = (const float*)d_in[3];
    const int*   eidx   = (const int*)d_in[4];   // [2, E]: row0=src, row1=dst
    const float* eattr  = (const float*)d_in[5];
    const int*   psrc   = (const int*)d_in[6];
    const int*   pdst   = (const int*)d_in[7];
    const float* pattr  = (const float*)d_in[8];

    const int n_coarse = in_sizes[0] / CIN;      // 200000
    const int n_edges  = in_sizes[4] / 2;        // 3200000
    const int n_pool   = in_sizes[6];            // 2400000
    const int n_fine   = out_size / COUT;        // 800000

    const int* esrc = eidx;
    const int* edst = eidx + n_edges;

    // ws layout (102.4 MB, same footprint as the proven round-0 kernel):
    float* h = (float*)d_ws;                       // [Nc, 64]  51.2 MB
    float* m = h + (size_t)n_coarse * COUT;        // [Nc, 64]  51.2 MB

    // Edge-phase scratch lives in d_out (dead until pool_gather overwrites it):
    //   entries1: n_edges * 16 B = 51.2 MB at offset 0
    //   head1:    n_coarse * 4 B = 0.8 MB after it
    char* outb = (char*)d_out;
    int4* entries1 = (int4*)outb;
    int*  head1    = (int*)(outb + (size_t)n_edges * sizeof(int4));

    // Pool-phase scratch overlays m (dead after edge_gather):
    //   entries2: n_pool * 16 B = 38.4 MB, head2: n_fine * 4 B = 3.2 MB
    char* mb = (char*)m;
    int4* entries2 = (int4*)mb;
    int*  head2    = (int*)(mb + (size_t)n_pool * sizeof(int4));

    // 1) head1 = -1
    hipMemsetAsync(head1, 0xFF, (size_t)n_coarse * sizeof(int), stream);

    // 2) dense transforms: h = x@Wr + b, m = x@Wn
    gemm_hm_kernel<<<(n_coarse + 31) / 32, 256, 0, stream>>>(x, W_root, W_nbr, b, h, m, n_coarse);

    // 3) build edge lists (into d_out scratch)
    build_lists_kernel<<<(n_edges + 255) / 256, 256, 0, stream>>>(
        esrc, edst, eattr, head1, entries1, n_edges);

    // 4) edge aggregation: h += sum over in-edges of m[src]*w
    edge_gather_kernel<<<(n_coarse + 3) / 4, 256, 0, stream>>>(
        m, head1, entries1, h, n_coarse);

    // 5) head2 = -1 (m buffer is now dead; reuse it)
    hipMemsetAsync(head2, 0xFF, (size_t)n_fine * sizeof(int), stream);

    // 6) build pool lists (into m scratch)
    build_lists_kernel<<<(n_pool + 255) / 256, 256, 0, stream>>>(
        psrc, pdst, pattr, head2, entries2, n_pool);

    // 7) unpool gather: every output row written exactly once
    pool_gather_kernel<<<(n_fine + 3) / 4, 256, 0, stream>>>(
        h, head2, entries2, (float*)d_out, n_fine);
}